// Round 12
// baseline (529.899 us; speedup 1.0000x reference)
//
#include <hip/hip_runtime.h>
#include <cstddef>
#include <cstdint>

#define D 128
#define BN_EPS 1e-5f
#define BKT_SH 9               // 512 nodes per bucket
#define BKT_N 512
#define ABLK 256               // blocks in bucket passes
#define NBMLP 1024             // fixed mlp grid (grid-stride over tiles)

typedef _Float16 f16x8 __attribute__((ext_vector_type(8)));
typedef float f32x4 __attribute__((ext_vector_type(4)));

__device__ __forceinline__ ushort f2h(float f) {
    _Float16 h = (_Float16)f;
    ushort s;
    __builtin_memcpy(&s, &h, 2);
    return s;
}
__device__ __forceinline__ float hlo(uint v) {
    ushort s = (ushort)(v & 0xffffu);
    _Float16 h;
    __builtin_memcpy(&h, &s, 2);
    return (float)h;
}
__device__ __forceinline__ float hhi(uint v) {
    ushort s = (ushort)(v >> 16);
    _Float16 h;
    __builtin_memcpy(&h, &s, 2);
    return (float)h;
}

// fused: ss identity init + stats zero
__global__ void k_init(float* ss, float* stats_mid, int nstats) {
    int i = blockIdx.x * blockDim.x + threadIdx.x;
    if (i < 128) {
        ss[i] = 1.f;
        ss[128 + i] = 0.f;
    }
    if (i < nstats) stats_mid[i] = 0.f;
}

// ---------------- bucketed CSR build (no global atomics) ----------------
__global__ __launch_bounds__(256) void k_bcount(const int* __restrict__ dst, int E, int CH,
                                                int nbkt, int* __restrict__ bcnt) {
    __shared__ int h[256];
    int tid = threadIdx.x;
    h[tid] = 0;
    __syncthreads();
    int s = blockIdx.x * CH, e = s + CH;
    if (e > E) e = E;
    for (int i = s + tid; i < e; i += 256) atomicAdd(&h[dst[i] >> BKT_SH], 1);
    __syncthreads();
    if (tid < nbkt) bcnt[tid * ABLK + blockIdx.x] = h[tid];
}

__global__ __launch_bounds__(256) void k_bscan(const int* __restrict__ bcnt, int nbkt,
                                               int* __restrict__ boff, int* __restrict__ bbase,
                                               int* __restrict__ row_start, int N, int E) {
    __shared__ int tot[256];
    int b = threadIdx.x;
    int t = 0;
    if (b < nbkt) {
        for (int i = 0; i < ABLK; ++i) {
            boff[b * ABLK + i] = t;
            t += bcnt[b * ABLK + i];
        }
    }
    tot[b] = t;
    __syncthreads();
    int v = t;
    for (int off = 1; off < 256; off <<= 1) {
        int u = (b >= off) ? tot[b - off] : 0;
        __syncthreads();
        tot[b] += u;
        __syncthreads();
    }
    if (b < nbkt) bbase[b] = tot[b] - v;
    if (b == 0) {
        bbase[nbkt] = E;
        row_start[N] = E;
    }
}

__global__ __launch_bounds__(256) void k_bscatter(const int* __restrict__ src,
                                                  const int* __restrict__ dst, int E, int CH,
                                                  int nbkt, const int* __restrict__ boff,
                                                  const int* __restrict__ bbase,
                                                  uint* __restrict__ staged) {
    __shared__ int cur[256];
    int tid = threadIdx.x;
    if (tid < nbkt) cur[tid] = bbase[tid] + boff[tid * ABLK + blockIdx.x];
    __syncthreads();
    int s = blockIdx.x * CH, e = s + CH;
    if (e > E) e = E;
    for (int i = s + tid; i < e; i += 256) {
        int d = dst[i];
        int b = d >> BKT_SH;
        int pos = atomicAdd(&cur[b], 1);
        staged[pos] = ((uint)(d & (BKT_N - 1)) << 23) | (uint)src[i];
    }
}

__global__ __launch_bounds__(256) void k_bfill(const uint* __restrict__ staged,
                                               const int* __restrict__ bbase, int N,
                                               int* __restrict__ row_start,
                                               int* __restrict__ col_idx) {
    __shared__ int cnt[BKT_N];
    __shared__ int sc[256];
    __shared__ int cur[BKT_N];
    int b = blockIdx.x, tid = threadIdx.x;
    cnt[tid] = 0;
    cnt[tid + 256] = 0;
    __syncthreads();
    int ebase = bbase[b], eend = bbase[b + 1];
    for (int i = ebase + tid; i < eend; i += 256) atomicAdd(&cnt[staged[i] >> 23], 1);
    __syncthreads();
    int c0 = cnt[2 * tid], c1 = cnt[2 * tid + 1], s = c0 + c1;
    sc[tid] = s;
    __syncthreads();
    for (int off = 1; off < 256; off <<= 1) {
        int u = (tid >= off) ? sc[tid - off] : 0;
        __syncthreads();
        sc[tid] += u;
        __syncthreads();
    }
    int ex = sc[tid] - s;
    int g0 = (b << BKT_SH) + 2 * tid;
    int p0 = ebase + ex, p1 = ebase + ex + c0;
    cur[2 * tid] = p0;
    cur[2 * tid + 1] = p1;
    if (g0 < N) row_start[g0] = p0;
    if (g0 + 1 < N) row_start[g0 + 1] = p1;
    __syncthreads();
    for (int i = ebase + tid; i < eend; i += 256) {
        uint w = staged[i];
        int pos = atomicAdd(&cur[w >> 23], 1);
        col_idx[pos] = (int)(w & 0x7FFFFFu);
    }
}

// ---------------- fp32 -> fp16 convert ----------------
__global__ void k_convert(const float* __restrict__ x, uint* __restrict__ xh, int nd8) {
    int i = blockIdx.x * blockDim.x + threadIdx.x;
    if (i >= nd8) return;
    size_t off = (size_t)i * 8;
    const float4* p = (const float4*)(x + off);
    float4 v0 = p[0], v1 = p[1];
    uint4 o;
    o.x = (uint)f2h(v0.x) | ((uint)f2h(v0.y) << 16);
    o.y = (uint)f2h(v0.z) | ((uint)f2h(v0.w) << 16);
    o.z = (uint)f2h(v1.x) | ((uint)f2h(v1.y) << 16);
    o.w = (uint)f2h(v1.z) | ((uint)f2h(v1.w) << 16);
    *(uint4*)(xh + off / 2) = o;
}

// ---------------- weight prep: fp32 W[k][c] -> fp16 Wt[c][k] ----------------
__global__ __launch_bounds__(256) void k_prep_w(const float* __restrict__ W,
                                                ushort* __restrict__ Wt) {
    const float* src = W + (size_t)blockIdx.x * D * D;
    ushort* dst = Wt + (size_t)blockIdx.x * D * D;
#pragma unroll
    for (int i = 0; i < 64; ++i) {
        int idx = i * 256 + threadIdx.x;
        int k = idx >> 7, c = idx & 127;
        dst[c * D + k] = f2h(src[idx]);
    }
}

// ---------------- gather + BN affine, QUARTER-ROW passes ----------------
// gridDim.y = 4: pass q covers feature cols [q*32, q*32+32). Per-pass random
// working set 6.4 MB (vs 4 MB/XCD L2). 4 lanes/node (64B), 64 nodes/block.
__global__ __launch_bounds__(256) void k_gather(const uint* __restrict__ xh,
                                                const int* __restrict__ rs,
                                                const int* __restrict__ col,
                                                const float* __restrict__ ssin, int n,
                                                uint* __restrict__ U) {
    int tid = threadIdx.x;
    int l4 = tid & 3;
    int q = blockIdx.y;
    int node = blockIdx.x * 64 + (tid >> 2);
    if (node >= n) return;
    const int cb = q * 32 + l4 * 8;
    const float4 A0 = *(const float4*)(ssin + cb);
    const float4 A1 = *(const float4*)(ssin + cb + 4);
    const float4 B0 = *(const float4*)(ssin + 128 + cb);
    const float4 B1 = *(const float4*)(ssin + 128 + cb + 4);
    const uint4* xr = (const uint4*)xh + q * 4 + l4;  // row r at xr[r*16]
    uint4 v = xr[(size_t)node * 16];
    float a0 = hlo(v.x), a1 = hhi(v.x), a2 = hlo(v.y), a3 = hhi(v.y);
    float a4 = hlo(v.z), a5 = hhi(v.z), a6 = hlo(v.w), a7 = hhi(v.w);
    int j0 = rs[node], e = rs[node + 1];
    int j = j0;
    for (; j + 4 <= e; j += 4) {
        int c0 = col[j], c1 = col[j + 1], c2 = col[j + 2], c3 = col[j + 3];
        uint4 u0 = xr[(size_t)c0 * 16];
        uint4 u1 = xr[(size_t)c1 * 16];
        uint4 u2 = xr[(size_t)c2 * 16];
        uint4 u3 = xr[(size_t)c3 * 16];
        a0 += (hlo(u0.x) + hlo(u1.x)) + (hlo(u2.x) + hlo(u3.x));
        a1 += (hhi(u0.x) + hhi(u1.x)) + (hhi(u2.x) + hhi(u3.x));
        a2 += (hlo(u0.y) + hlo(u1.y)) + (hlo(u2.y) + hlo(u3.y));
        a3 += (hhi(u0.y) + hhi(u1.y)) + (hhi(u2.y) + hhi(u3.y));
        a4 += (hlo(u0.z) + hlo(u1.z)) + (hlo(u2.z) + hlo(u3.z));
        a5 += (hhi(u0.z) + hhi(u1.z)) + (hhi(u2.z) + hhi(u3.z));
        a6 += (hlo(u0.w) + hlo(u1.w)) + (hlo(u2.w) + hlo(u3.w));
        a7 += (hhi(u0.w) + hhi(u1.w)) + (hhi(u2.w) + hhi(u3.w));
    }
    for (; j < e; ++j) {
        uint4 u = xr[(size_t)col[j] * 16];
        a0 += hlo(u.x);
        a1 += hhi(u.x);
        a2 += hlo(u.y);
        a3 += hhi(u.y);
        a4 += hlo(u.z);
        a5 += hhi(u.z);
        a6 += hlo(u.w);
        a7 += hhi(u.w);
    }
    float cnt = (float)(e - j0 + 1);
    float r0 = fmaf(A0.x, a0, cnt * B0.x);
    float r1 = fmaf(A0.y, a1, cnt * B0.y);
    float r2 = fmaf(A0.z, a2, cnt * B0.z);
    float r3 = fmaf(A0.w, a3, cnt * B0.w);
    float r4 = fmaf(A1.x, a4, cnt * B1.x);
    float r5 = fmaf(A1.y, a5, cnt * B1.y);
    float r6 = fmaf(A1.z, a6, cnt * B1.z);
    float r7 = fmaf(A1.w, a7, cnt * B1.w);
    uint4 o;
    o.x = (uint)f2h(r0) | ((uint)f2h(r1) << 16);
    o.y = (uint)f2h(r2) | ((uint)f2h(r3) << 16);
    o.z = (uint)f2h(r4) | ((uint)f2h(r5) << 16);
    o.w = (uint)f2h(r6) | ((uint)f2h(r7) << 16);
    ((uint4*)U)[(size_t)node * 16 + q * 4 + l4] = o;
}

// ---------------- MLP: weights register-resident, grid-stride over 32-row tiles --------
__global__ __launch_bounds__(128) void k_mlp(const ushort* __restrict__ U,
                                             const ushort* __restrict__ Wt1,
                                             const float* __restrict__ b1,
                                             const ushort* __restrict__ Wt2,
                                             const float* __restrict__ b2,
                                             ushort* __restrict__ hout,
                                             float* __restrict__ stats_mid, int n,
                                             int ntiles) {
    __shared__ ushort Hs[32 * D];  // 8 KB h1 tile, XOR-swizzled by 16B chunk
    __shared__ float sred[256];
    const int tid = threadIdx.x;
    sred[tid] = 0.f;
    sred[128 + tid] = 0.f;

    const int lane = tid & 63;
    const int wn = tid >> 6;  // column half
    const int l15 = lane & 15, lk = lane >> 4;

    // ---- hoist weight fragments into registers (once per block) ----
    f16x8 w1[4][4], w2[4][4];  // [ks][nn]
#pragma unroll
    for (int ks = 0; ks < 4; ++ks) {
        int k0 = ks * 32 + lk * 8;
#pragma unroll
        for (int nn = 0; nn < 4; ++nn) {
            int c = wn * 64 + nn * 16 + l15;
            w1[ks][nn] = *(const f16x8*)(Wt1 + (size_t)c * D + k0);
            w2[ks][nn] = *(const f16x8*)(Wt2 + (size_t)c * D + k0);
        }
    }
    float bc1[4], bc2[4];
#pragma unroll
    for (int nn = 0; nn < 4; ++nn) {
        bc1[nn] = b1[wn * 64 + nn * 16 + l15];
        bc2[nn] = b2[wn * 64 + nn * 16 + l15];
    }
    float cs[4] = {0.f, 0.f, 0.f, 0.f}, cq[4] = {0.f, 0.f, 0.f, 0.f};

    for (int t = blockIdx.x; t < ntiles; t += NBMLP) {
        const int rb = t * 32;
        f16x8 a[2][4];  // [m][ks]
#pragma unroll
        for (int ks = 0; ks < 4; ++ks) {
            int k0 = ks * 32 + lk * 8;
#pragma unroll
            for (int m = 0; m < 2; ++m) {
                int row = rb + m * 16 + l15;
                if (row > n - 1) row = n - 1;  // clamp; garbage rows never stored
                a[m][ks] = *(const f16x8*)(U + (size_t)row * D + k0);
            }
        }

        f32x4 acc[2][4];
#pragma unroll
        for (int m = 0; m < 2; ++m)
#pragma unroll
            for (int nn = 0; nn < 4; ++nn) acc[m][nn] = (f32x4){0.f, 0.f, 0.f, 0.f};

        // GEMM1 (all operands in registers)
#pragma unroll
        for (int ks = 0; ks < 4; ++ks)
#pragma unroll
            for (int m = 0; m < 2; ++m)
#pragma unroll
                for (int nn = 0; nn < 4; ++nn)
                    acc[m][nn] = __builtin_amdgcn_mfma_f32_16x16x32_f16(a[m][ks], w1[ks][nn],
                                                                        acc[m][nn], 0, 0, 0);

        __syncthreads();  // prev tile's GEMM2 reads of Hs complete before overwrite
        // epilogue1: h1 = relu(acc + b1) -> Hs (fp16, swizzled)
#pragma unroll
        for (int nn = 0; nn < 4; ++nn) {
            int cout = wn * 64 + nn * 16 + l15;
            int chv = cout >> 3, cw = cout & 7;
#pragma unroll
            for (int m = 0; m < 2; ++m)
#pragma unroll
                for (int r = 0; r < 4; ++r) {
                    int row = m * 16 + lk * 4 + r;
                    float v = fmaxf(acc[m][nn][r] + bc1[nn], 0.f);
                    Hs[row * D + ((chv ^ (row & 15)) << 3) + cw] = f2h(v);
                }
        }
        __syncthreads();

        // GEMM2: A = h1 from LDS, B = w2 registers
#pragma unroll
        for (int m = 0; m < 2; ++m)
#pragma unroll
            for (int nn = 0; nn < 4; ++nn) acc[m][nn] = (f32x4){0.f, 0.f, 0.f, 0.f};
#pragma unroll
        for (int ks = 0; ks < 4; ++ks) {
            f16x8 ah[2];
#pragma unroll
            for (int m = 0; m < 2; ++m) {
                int row = m * 16 + l15;
                ah[m] = *(const f16x8*)(Hs + row * D + (((ks * 4 + lk) ^ l15) << 3));
            }
#pragma unroll
            for (int m = 0; m < 2; ++m)
#pragma unroll
                for (int nn = 0; nn < 4; ++nn)
                    acc[m][nn] = __builtin_amdgcn_mfma_f32_16x16x32_f16(ah[m], w2[ks][nn],
                                                                        acc[m][nn], 0, 0, 0);
        }

        // epilogue2: h2 = relu(acc + b2) -> global fp16 + register stats
#pragma unroll
        for (int nn = 0; nn < 4; ++nn) {
            int c = wn * 64 + nn * 16 + l15;
#pragma unroll
            for (int m = 0; m < 2; ++m) {
                int rbase = rb + m * 16 + lk * 4;
#pragma unroll
                for (int r = 0; r < 4; ++r) {
                    if (rbase + r < n) {
                        float v = fmaxf(acc[m][nn][r] + bc2[nn], 0.f);
                        hout[(size_t)(rbase + r) * D + c] = f2h(v);
                        cs[nn] += v;
                        cq[nn] = fmaf(v, v, cq[nn]);
                    }
                }
            }
        }
    }

    // fold per-thread stats -> LDS -> 32-sliced global atomics
#pragma unroll
    for (int nn = 0; nn < 4; ++nn) {
        int c = wn * 64 + nn * 16 + l15;
        atomicAdd(&sred[c], cs[nn]);
        atomicAdd(&sred[128 + c], cq[nn]);
    }
    __syncthreads();
    float* sm = stats_mid + (size_t)(blockIdx.x & 31) * 256;
    atomicAdd(&sm[tid], sred[tid]);
    atomicAdd(&sm[128 + tid], sred[128 + tid]);
}

// ---------------- BN finalize -> affine (a,b) ----------------
__global__ __launch_bounds__(128) void k_bnfin(const float* __restrict__ sm,
                                               const float* __restrict__ gamma,
                                               const float* __restrict__ beta, float ninv,
                                               float* __restrict__ ss) {
    int c = threadIdx.x;
    float s = 0.f, q = 0.f;
    for (int r = 0; r < 32; ++r) {
        s += sm[r * 256 + c];
        q += sm[r * 256 + 128 + c];
    }
    float mean = s * ninv;
    float var = fmaxf(q * ninv - mean * mean, 0.f);
    float a = gamma[c] * rsqrtf(var + BN_EPS);
    ss[c] = a;
    ss[128 + c] = beta[c] - mean * a;
}

// ---------------- final normalize: out = a*h + b (fp32) ----------------
__global__ void k_norm_final(const uint* __restrict__ h, const float* __restrict__ ss, int nd8,
                             float* __restrict__ out) {
    int i = blockIdx.x * blockDim.x + threadIdx.x;
    if (i >= nd8) return;
    size_t off = (size_t)i * 8;
    int c = (int)(off & (D - 1));
    uint4 v = *(const uint4*)(h + off / 2);
    float4 a0 = *(const float4*)(ss + c), a1 = *(const float4*)(ss + c + 4);
    float4 b0 = *(const float4*)(ss + 128 + c), b1 = *(const float4*)(ss + 132 + c);
    float4 o0, o1;
    o0.x = fmaf(hlo(v.x), a0.x, b0.x);
    o0.y = fmaf(hhi(v.x), a0.y, b0.y);
    o0.z = fmaf(hlo(v.y), a0.z, b0.z);
    o0.w = fmaf(hhi(v.y), a0.w, b0.w);
    o1.x = fmaf(hlo(v.z), a1.x, b1.x);
    o1.y = fmaf(hhi(v.z), a1.y, b1.y);
    o1.z = fmaf(hlo(v.w), a1.z, b1.z);
    o1.w = fmaf(hhi(v.w), a1.w, b1.w);
    *(float4*)(out + off) = o0;
    *(float4*)(out + off + 4) = o1;
}

extern "C" void kernel_launch(void* const* d_in, const int* in_sizes, int n_in, void* d_out,
                              int out_size, void* d_ws, size_t ws_size, hipStream_t stream) {
    const float* x = (const float*)d_in[0];
    const int* esrc = (const int*)d_in[1];
    const int* edst = (const int*)d_in[2];
    const float* W1 = (const float*)d_in[3];
    const float* b1 = (const float*)d_in[4];
    const float* W2 = (const float*)d_in[5];
    const float* b2 = (const float*)d_in[6];
    const float* gamma = (const float*)d_in[7];
    const float* beta = (const float*)d_in[8];

    const int N = in_sizes[0] / D;
    const int E = in_sizes[1];
    const int L = in_sizes[3] / (D * D);
    const size_t nd = (size_t)N * D;
    const int nd8 = (int)(nd / 8);
    const int nbkt = (N + BKT_N - 1) >> BKT_SH;
    const int CH = (E + ABLK - 1) / ABLK;
    const int ntiles = (N + 31) / 32;

    // workspace layout (16B-aligned blocks first)
    char* ws = (char*)d_ws;
    uint* xh = (uint*)ws;          ws += nd * 2;                  // fp16 input
    uint* act0 = (uint*)ws;        ws += nd * 2;                  // ping
    uint* act1 = (uint*)ws;        ws += nd * 2;                  // pong
    uint* ubuf = (uint*)ws;        ws += nd * 2;                  // pre-affined MLP input u
    ushort* Wt1 = (ushort*)ws;     ws += (size_t)L * D * D * 2;
    ushort* Wt2 = (ushort*)ws;     ws += (size_t)L * D * D * 2;
    uint* staged = (uint*)ws;      ws += (size_t)E * 4;
    int* col_idx = (int*)ws;       ws += (size_t)E * 4;
    int* bcnt = (int*)ws;          ws += 256 * ABLK * 4;
    int* boff = (int*)ws;          ws += 256 * ABLK * 4;
    float* stats_mid = (float*)ws; ws += (size_t)3 * 32 * 256 * 4;  // per-layer regions
    float* ssall = (float*)ws;     ws += (size_t)(L + 1) * 256 * 4;
    int* bbase = (int*)ws;         ws += (256 + 1) * 4;
    int* row_start = (int*)ws;     ws += (size_t)(N + 1) * 4;

    // ---- one-time prep ----
    k_convert<<<(nd8 + 255) / 256, 256, 0, stream>>>(x, xh, nd8);
    k_prep_w<<<L, 256, 0, stream>>>(W1, Wt1);
    k_prep_w<<<L, 256, 0, stream>>>(W2, Wt2);
    k_init<<<(3 * 32 * 256 + 255) / 256, 256, 0, stream>>>(ssall, stats_mid, 3 * 32 * 256);

    // ---- bucketed CSR build ----
    k_bcount<<<ABLK, 256, 0, stream>>>(edst, E, CH, nbkt, bcnt);
    k_bscan<<<1, 256, 0, stream>>>(bcnt, nbkt, boff, bbase, row_start, N, E);
    k_bscatter<<<ABLK, 256, 0, stream>>>(esrc, edst, E, CH, nbkt, boff, bbase, staged);
    k_bfill<<<nbkt, 256, 0, stream>>>(staged, bbase, N, row_start, col_idx);

    uint* bufs[2] = {act0, act1};
    const uint* cur_in = xh;
    dim3 ggrid((N + 63) / 64, 4);
    for (int l = 0; l < L; ++l) {
        uint* cur_out = bufs[l & 1];
        k_gather<<<ggrid, 256, 0, stream>>>(cur_in, row_start, col_idx,
                                            ssall + (size_t)l * 256, N, ubuf);
        k_mlp<<<NBMLP, 128, 0, stream>>>((const ushort*)ubuf, Wt1 + (size_t)l * D * D,
                                         b1 + (size_t)l * D, Wt2 + (size_t)l * D * D,
                                         b2 + (size_t)l * D, (ushort*)cur_out,
                                         stats_mid + (size_t)l * 32 * 256, N, ntiles);
        k_bnfin<<<1, 128, 0, stream>>>(stats_mid + (size_t)l * 32 * 256, gamma + (size_t)l * D,
                                       beta + (size_t)l * D, 1.0f / (float)N,
                                       ssall + (size_t)(l + 1) * 256);
        cur_in = cur_out;
    }
    k_norm_final<<<(nd8 + 255) / 256, 256, 0, stream>>>((const uint*)cur_in,
                                                        ssall + (size_t)L * 256, nd8,
                                                        (float*)d_out);
}

// Round 13
// 389.583 us; speedup vs baseline: 1.3602x; 1.3602x over previous
//
#include <hip/hip_runtime.h>
#include <cstddef>
#include <cstdint>

#define D 128
#define BN_EPS 1e-5f
#define BKT_SH 9               // 512 nodes per bucket
#define BKT_N 512
#define ABLK 256               // blocks in bucket passes
#define NBMLP 1024             // fixed mlp grid (grid-stride over tiles)

typedef _Float16 f16x8 __attribute__((ext_vector_type(8)));
typedef float f32x4 __attribute__((ext_vector_type(4)));

__device__ __forceinline__ ushort f2h(float f) {
    _Float16 h = (_Float16)f;
    ushort s;
    __builtin_memcpy(&s, &h, 2);
    return s;
}
__device__ __forceinline__ float hlo(uint v) {
    ushort s = (ushort)(v & 0xffffu);
    _Float16 h;
    __builtin_memcpy(&h, &s, 2);
    return (float)h;
}
__device__ __forceinline__ float hhi(uint v) {
    ushort s = (ushort)(v >> 16);
    _Float16 h;
    __builtin_memcpy(&h, &s, 2);
    return (float)h;
}

// fused: ss identity init + stats zero
__global__ void k_init(float* ss, float* stats_mid, int nstats) {
    int i = blockIdx.x * blockDim.x + threadIdx.x;
    if (i < 128) {
        ss[i] = 1.f;
        ss[128 + i] = 0.f;
    }
    if (i < nstats) stats_mid[i] = 0.f;
}

// ---------------- bucketed CSR build (no global atomics) ----------------
__global__ __launch_bounds__(256) void k_bcount(const int* __restrict__ dst, int E, int CH,
                                                int nbkt, int* __restrict__ bcnt) {
    __shared__ int h[256];
    int tid = threadIdx.x;
    h[tid] = 0;
    __syncthreads();
    int s = blockIdx.x * CH, e = s + CH;
    if (e > E) e = E;
    for (int i = s + tid; i < e; i += 256) atomicAdd(&h[dst[i] >> BKT_SH], 1);
    __syncthreads();
    if (tid < nbkt) bcnt[tid * ABLK + blockIdx.x] = h[tid];
}

__global__ __launch_bounds__(256) void k_bscan(const int* __restrict__ bcnt, int nbkt,
                                               int* __restrict__ boff, int* __restrict__ bbase,
                                               int* __restrict__ row_start, int N, int E) {
    __shared__ int tot[256];
    int b = threadIdx.x;
    int t = 0;
    if (b < nbkt) {
        for (int i = 0; i < ABLK; ++i) {
            boff[b * ABLK + i] = t;
            t += bcnt[b * ABLK + i];
        }
    }
    tot[b] = t;
    __syncthreads();
    int v = t;
    for (int off = 1; off < 256; off <<= 1) {
        int u = (b >= off) ? tot[b - off] : 0;
        __syncthreads();
        tot[b] += u;
        __syncthreads();
    }
    if (b < nbkt) bbase[b] = tot[b] - v;
    if (b == 0) {
        bbase[nbkt] = E;
        row_start[N] = E;
    }
}

__global__ __launch_bounds__(256) void k_bscatter(const int* __restrict__ src,
                                                  const int* __restrict__ dst, int E, int CH,
                                                  int nbkt, const int* __restrict__ boff,
                                                  const int* __restrict__ bbase,
                                                  uint* __restrict__ staged) {
    __shared__ int cur[256];
    int tid = threadIdx.x;
    if (tid < nbkt) cur[tid] = bbase[tid] + boff[tid * ABLK + blockIdx.x];
    __syncthreads();
    int s = blockIdx.x * CH, e = s + CH;
    if (e > E) e = E;
    for (int i = s + tid; i < e; i += 256) {
        int d = dst[i];
        int b = d >> BKT_SH;
        int pos = atomicAdd(&cur[b], 1);
        staged[pos] = ((uint)(d & (BKT_N - 1)) << 23) | (uint)src[i];
    }
}

__global__ __launch_bounds__(256) void k_bfill(const uint* __restrict__ staged,
                                               const int* __restrict__ bbase, int N,
                                               int* __restrict__ row_start,
                                               int* __restrict__ col_idx) {
    __shared__ int cnt[BKT_N];
    __shared__ int sc[256];
    __shared__ int cur[BKT_N];
    int b = blockIdx.x, tid = threadIdx.x;
    cnt[tid] = 0;
    cnt[tid + 256] = 0;
    __syncthreads();
    int ebase = bbase[b], eend = bbase[b + 1];
    for (int i = ebase + tid; i < eend; i += 256) atomicAdd(&cnt[staged[i] >> 23], 1);
    __syncthreads();
    int c0 = cnt[2 * tid], c1 = cnt[2 * tid + 1], s = c0 + c1;
    sc[tid] = s;
    __syncthreads();
    for (int off = 1; off < 256; off <<= 1) {
        int u = (tid >= off) ? sc[tid - off] : 0;
        __syncthreads();
        sc[tid] += u;
        __syncthreads();
    }
    int ex = sc[tid] - s;
    int g0 = (b << BKT_SH) + 2 * tid;
    int p0 = ebase + ex, p1 = ebase + ex + c0;
    cur[2 * tid] = p0;
    cur[2 * tid + 1] = p1;
    if (g0 < N) row_start[g0] = p0;
    if (g0 + 1 < N) row_start[g0 + 1] = p1;
    __syncthreads();
    for (int i = ebase + tid; i < eend; i += 256) {
        uint w = staged[i];
        int pos = atomicAdd(&cur[w >> 23], 1);
        col_idx[pos] = (int)(w & 0x7FFFFFu);
    }
}

// ---------------- fp32 -> fp16 convert ----------------
__global__ void k_convert(const float* __restrict__ x, uint* __restrict__ xh, int nd8) {
    int i = blockIdx.x * blockDim.x + threadIdx.x;
    if (i >= nd8) return;
    size_t off = (size_t)i * 8;
    const float4* p = (const float4*)(x + off);
    float4 v0 = p[0], v1 = p[1];
    uint4 o;
    o.x = (uint)f2h(v0.x) | ((uint)f2h(v0.y) << 16);
    o.y = (uint)f2h(v0.z) | ((uint)f2h(v0.w) << 16);
    o.z = (uint)f2h(v1.x) | ((uint)f2h(v1.y) << 16);
    o.w = (uint)f2h(v1.z) | ((uint)f2h(v1.w) << 16);
    *(uint4*)(xh + off / 2) = o;
}

// ---------------- weight prep: both W1,W2 fp32 [k][c] -> fp16 [c][k], one launch ----
__global__ __launch_bounds__(256) void k_prep_w(const float* __restrict__ W1,
                                                const float* __restrict__ W2,
                                                ushort* __restrict__ Wt1,
                                                ushort* __restrict__ Wt2) {
    const float* src1 = W1 + (size_t)blockIdx.x * D * D;
    const float* src2 = W2 + (size_t)blockIdx.x * D * D;
    ushort* dst1 = Wt1 + (size_t)blockIdx.x * D * D;
    ushort* dst2 = Wt2 + (size_t)blockIdx.x * D * D;
#pragma unroll
    for (int i = 0; i < 64; ++i) {
        int idx = i * 256 + threadIdx.x;
        int k = idx >> 7, c = idx & 127;
        dst1[c * D + k] = f2h(src1[idx]);
        dst2[c * D + k] = f2h(src2[idx]);
    }
}

// ---------------- gather + BN affine, HALF-ROW passes, unroll 8 ----------------
// gridDim.y = 2: pass y covers cols [y*64, y*64+64) = exactly one 128B line per
// node -> no line amplification, 12.8 MB working set per pass. 8 lanes/node,
// 32 nodes/block. Unroll 8 -> 8x128B in flight per node stream (latency hiding).
__global__ __launch_bounds__(256) void k_gather(const uint* __restrict__ xh,
                                                const int* __restrict__ rs,
                                                const int* __restrict__ col,
                                                const float* __restrict__ ssin, int n,
                                                uint* __restrict__ U) {
    int tid = threadIdx.x;
    int l8 = tid & 7;
    int half = blockIdx.y;
    int node = blockIdx.x * 32 + (tid >> 3);
    if (node >= n) return;
    const int cb = half * 64 + l8 * 8;
    const float4 A0 = *(const float4*)(ssin + cb);
    const float4 A1 = *(const float4*)(ssin + cb + 4);
    const float4 B0 = *(const float4*)(ssin + 128 + cb);
    const float4 B1 = *(const float4*)(ssin + 128 + cb + 4);
    const uint4* xr = (const uint4*)xh + half * 8 + l8;  // row r at xr[r*16]
    uint4 v = xr[(size_t)node * 16];
    float a0 = hlo(v.x), a1 = hhi(v.x), a2 = hlo(v.y), a3 = hhi(v.y);
    float a4 = hlo(v.z), a5 = hhi(v.z), a6 = hlo(v.w), a7 = hhi(v.w);
    int j0 = rs[node], e = rs[node + 1];
    int j = j0;
    for (; j + 8 <= e; j += 8) {
        uint4 u0 = xr[(size_t)col[j] * 16];
        uint4 u1 = xr[(size_t)col[j + 1] * 16];
        uint4 u2 = xr[(size_t)col[j + 2] * 16];
        uint4 u3 = xr[(size_t)col[j + 3] * 16];
        uint4 u4 = xr[(size_t)col[j + 4] * 16];
        uint4 u5 = xr[(size_t)col[j + 5] * 16];
        uint4 u6 = xr[(size_t)col[j + 6] * 16];
        uint4 u7 = xr[(size_t)col[j + 7] * 16];
        a0 += ((hlo(u0.x) + hlo(u1.x)) + (hlo(u2.x) + hlo(u3.x))) +
              ((hlo(u4.x) + hlo(u5.x)) + (hlo(u6.x) + hlo(u7.x)));
        a1 += ((hhi(u0.x) + hhi(u1.x)) + (hhi(u2.x) + hhi(u3.x))) +
              ((hhi(u4.x) + hhi(u5.x)) + (hhi(u6.x) + hhi(u7.x)));
        a2 += ((hlo(u0.y) + hlo(u1.y)) + (hlo(u2.y) + hlo(u3.y))) +
              ((hlo(u4.y) + hlo(u5.y)) + (hlo(u6.y) + hlo(u7.y)));
        a3 += ((hhi(u0.y) + hhi(u1.y)) + (hhi(u2.y) + hhi(u3.y))) +
              ((hhi(u4.y) + hhi(u5.y)) + (hhi(u6.y) + hhi(u7.y)));
        a4 += ((hlo(u0.z) + hlo(u1.z)) + (hlo(u2.z) + hlo(u3.z))) +
              ((hlo(u4.z) + hlo(u5.z)) + (hlo(u6.z) + hlo(u7.z)));
        a5 += ((hhi(u0.z) + hhi(u1.z)) + (hhi(u2.z) + hhi(u3.z))) +
              ((hhi(u4.z) + hhi(u5.z)) + (hhi(u6.z) + hhi(u7.z)));
        a6 += ((hlo(u0.w) + hlo(u1.w)) + (hlo(u2.w) + hlo(u3.w))) +
              ((hlo(u4.w) + hlo(u5.w)) + (hlo(u6.w) + hlo(u7.w)));
        a7 += ((hhi(u0.w) + hhi(u1.w)) + (hhi(u2.w) + hhi(u3.w))) +
              ((hhi(u4.w) + hhi(u5.w)) + (hhi(u6.w) + hhi(u7.w)));
    }
    for (; j + 4 <= e; j += 4) {
        uint4 u0 = xr[(size_t)col[j] * 16];
        uint4 u1 = xr[(size_t)col[j + 1] * 16];
        uint4 u2 = xr[(size_t)col[j + 2] * 16];
        uint4 u3 = xr[(size_t)col[j + 3] * 16];
        a0 += (hlo(u0.x) + hlo(u1.x)) + (hlo(u2.x) + hlo(u3.x));
        a1 += (hhi(u0.x) + hhi(u1.x)) + (hhi(u2.x) + hhi(u3.x));
        a2 += (hlo(u0.y) + hlo(u1.y)) + (hlo(u2.y) + hlo(u3.y));
        a3 += (hhi(u0.y) + hhi(u1.y)) + (hhi(u2.y) + hhi(u3.y));
        a4 += (hlo(u0.z) + hlo(u1.z)) + (hlo(u2.z) + hlo(u3.z));
        a5 += (hhi(u0.z) + hhi(u1.z)) + (hhi(u2.z) + hhi(u3.z));
        a6 += (hlo(u0.w) + hlo(u1.w)) + (hlo(u2.w) + hlo(u3.w));
        a7 += (hhi(u0.w) + hhi(u1.w)) + (hhi(u2.w) + hhi(u3.w));
    }
    for (; j < e; ++j) {
        uint4 u = xr[(size_t)col[j] * 16];
        a0 += hlo(u.x);
        a1 += hhi(u.x);
        a2 += hlo(u.y);
        a3 += hhi(u.y);
        a4 += hlo(u.z);
        a5 += hhi(u.z);
        a6 += hlo(u.w);
        a7 += hhi(u.w);
    }
    float cnt = (float)(e - j0 + 1);
    float r0 = fmaf(A0.x, a0, cnt * B0.x);
    float r1 = fmaf(A0.y, a1, cnt * B0.y);
    float r2 = fmaf(A0.z, a2, cnt * B0.z);
    float r3 = fmaf(A0.w, a3, cnt * B0.w);
    float r4 = fmaf(A1.x, a4, cnt * B1.x);
    float r5 = fmaf(A1.y, a5, cnt * B1.y);
    float r6 = fmaf(A1.z, a6, cnt * B1.z);
    float r7 = fmaf(A1.w, a7, cnt * B1.w);
    uint4 o;
    o.x = (uint)f2h(r0) | ((uint)f2h(r1) << 16);
    o.y = (uint)f2h(r2) | ((uint)f2h(r3) << 16);
    o.z = (uint)f2h(r4) | ((uint)f2h(r5) << 16);
    o.w = (uint)f2h(r6) | ((uint)f2h(r7) << 16);
    ((uint4*)U)[(size_t)node * 16 + half * 8 + l8] = o;
}

// ---------------- MLP: weights register-resident, grid-stride over 32-row tiles --------
__global__ __launch_bounds__(128) void k_mlp(const ushort* __restrict__ U,
                                             const ushort* __restrict__ Wt1,
                                             const float* __restrict__ b1,
                                             const ushort* __restrict__ Wt2,
                                             const float* __restrict__ b2,
                                             ushort* __restrict__ hout,
                                             float* __restrict__ stats_mid, int n,
                                             int ntiles) {
    __shared__ ushort Hs[32 * D];  // 8 KB h1 tile, XOR-swizzled by 16B chunk
    __shared__ float sred[256];
    const int tid = threadIdx.x;
    sred[tid] = 0.f;
    sred[128 + tid] = 0.f;

    const int lane = tid & 63;
    const int wn = tid >> 6;  // column half
    const int l15 = lane & 15, lk = lane >> 4;

    // ---- hoist weight fragments into registers (once per block) ----
    f16x8 w1[4][4], w2[4][4];  // [ks][nn]
#pragma unroll
    for (int ks = 0; ks < 4; ++ks) {
        int k0 = ks * 32 + lk * 8;
#pragma unroll
        for (int nn = 0; nn < 4; ++nn) {
            int c = wn * 64 + nn * 16 + l15;
            w1[ks][nn] = *(const f16x8*)(Wt1 + (size_t)c * D + k0);
            w2[ks][nn] = *(const f16x8*)(Wt2 + (size_t)c * D + k0);
        }
    }
    float bc1[4], bc2[4];
#pragma unroll
    for (int nn = 0; nn < 4; ++nn) {
        bc1[nn] = b1[wn * 64 + nn * 16 + l15];
        bc2[nn] = b2[wn * 64 + nn * 16 + l15];
    }
    float cs[4] = {0.f, 0.f, 0.f, 0.f}, cq[4] = {0.f, 0.f, 0.f, 0.f};

    for (int t = blockIdx.x; t < ntiles; t += NBMLP) {
        const int rb = t * 32;
        f16x8 a[2][4];  // [m][ks]
#pragma unroll
        for (int ks = 0; ks < 4; ++ks) {
            int k0 = ks * 32 + lk * 8;
#pragma unroll
            for (int m = 0; m < 2; ++m) {
                int row = rb + m * 16 + l15;
                if (row > n - 1) row = n - 1;  // clamp; garbage rows never stored
                a[m][ks] = *(const f16x8*)(U + (size_t)row * D + k0);
            }
        }

        f32x4 acc[2][4];
#pragma unroll
        for (int m = 0; m < 2; ++m)
#pragma unroll
            for (int nn = 0; nn < 4; ++nn) acc[m][nn] = (f32x4){0.f, 0.f, 0.f, 0.f};

        // GEMM1 (all operands in registers)
#pragma unroll
        for (int ks = 0; ks < 4; ++ks)
#pragma unroll
            for (int m = 0; m < 2; ++m)
#pragma unroll
                for (int nn = 0; nn < 4; ++nn)
                    acc[m][nn] = __builtin_amdgcn_mfma_f32_16x16x32_f16(a[m][ks], w1[ks][nn],
                                                                        acc[m][nn], 0, 0, 0);

        __syncthreads();  // prev tile's GEMM2 reads of Hs complete before overwrite
        // epilogue1: h1 = relu(acc + b1) -> Hs (fp16, swizzled)
#pragma unroll
        for (int nn = 0; nn < 4; ++nn) {
            int cout = wn * 64 + nn * 16 + l15;
            int chv = cout >> 3, cw = cout & 7;
#pragma unroll
            for (int m = 0; m < 2; ++m)
#pragma unroll
                for (int r = 0; r < 4; ++r) {
                    int row = m * 16 + lk * 4 + r;
                    float v = fmaxf(acc[m][nn][r] + bc1[nn], 0.f);
                    Hs[row * D + ((chv ^ (row & 15)) << 3) + cw] = f2h(v);
                }
        }
        __syncthreads();

        // GEMM2: A = h1 from LDS, B = w2 registers
#pragma unroll
        for (int m = 0; m < 2; ++m)
#pragma unroll
            for (int nn = 0; nn < 4; ++nn) acc[m][nn] = (f32x4){0.f, 0.f, 0.f, 0.f};
#pragma unroll
        for (int ks = 0; ks < 4; ++ks) {
            f16x8 ah[2];
#pragma unroll
            for (int m = 0; m < 2; ++m) {
                int row = m * 16 + l15;
                ah[m] = *(const f16x8*)(Hs + row * D + (((ks * 4 + lk) ^ l15) << 3));
            }
#pragma unroll
            for (int m = 0; m < 2; ++m)
#pragma unroll
                for (int nn = 0; nn < 4; ++nn)
                    acc[m][nn] = __builtin_amdgcn_mfma_f32_16x16x32_f16(ah[m], w2[ks][nn],
                                                                        acc[m][nn], 0, 0, 0);
        }

        // epilogue2: h2 = relu(acc + b2) -> global fp16 + register stats
#pragma unroll
        for (int nn = 0; nn < 4; ++nn) {
            int c = wn * 64 + nn * 16 + l15;
#pragma unroll
            for (int m = 0; m < 2; ++m) {
                int rbase = rb + m * 16 + lk * 4;
#pragma unroll
                for (int r = 0; r < 4; ++r) {
                    if (rbase + r < n) {
                        float v = fmaxf(acc[m][nn][r] + bc2[nn], 0.f);
                        hout[(size_t)(rbase + r) * D + c] = f2h(v);
                        cs[nn] += v;
                        cq[nn] = fmaf(v, v, cq[nn]);
                    }
                }
            }
        }
    }

    // fold per-thread stats -> LDS -> 32-sliced global atomics
#pragma unroll
    for (int nn = 0; nn < 4; ++nn) {
        int c = wn * 64 + nn * 16 + l15;
        atomicAdd(&sred[c], cs[nn]);
        atomicAdd(&sred[128 + c], cq[nn]);
    }
    __syncthreads();
    float* sm = stats_mid + (size_t)(blockIdx.x & 31) * 256;
    atomicAdd(&sm[tid], sred[tid]);
    atomicAdd(&sm[128 + tid], sred[128 + tid]);
}

// ---------------- BN finalize -> affine (a,b) ----------------
__global__ __launch_bounds__(128) void k_bnfin(const float* __restrict__ sm,
                                               const float* __restrict__ gamma,
                                               const float* __restrict__ beta, float ninv,
                                               float* __restrict__ ss) {
    int c = threadIdx.x;
    float s = 0.f, q = 0.f;
    for (int r = 0; r < 32; ++r) {
        s += sm[r * 256 + c];
        q += sm[r * 256 + 128 + c];
    }
    float mean = s * ninv;
    float var = fmaxf(q * ninv - mean * mean, 0.f);
    float a = gamma[c] * rsqrtf(var + BN_EPS);
    ss[c] = a;
    ss[128 + c] = beta[c] - mean * a;
}

// ---------------- final normalize: out = a*h + b (fp32) ----------------
__global__ void k_norm_final(const uint* __restrict__ h, const float* __restrict__ ss, int nd8,
                             float* __restrict__ out) {
    int i = blockIdx.x * blockDim.x + threadIdx.x;
    if (i >= nd8) return;
    size_t off = (size_t)i * 8;
    int c = (int)(off & (D - 1));
    uint4 v = *(const uint4*)(h + off / 2);
    float4 a0 = *(const float4*)(ss + c), a1 = *(const float4*)(ss + c + 4);
    float4 b0 = *(const float4*)(ss + 128 + c), b1 = *(const float4*)(ss + 132 + c);
    float4 o0, o1;
    o0.x = fmaf(hlo(v.x), a0.x, b0.x);
    o0.y = fmaf(hhi(v.x), a0.y, b0.y);
    o0.z = fmaf(hlo(v.y), a0.z, b0.z);
    o0.w = fmaf(hhi(v.y), a0.w, b0.w);
    o1.x = fmaf(hlo(v.z), a1.x, b1.x);
    o1.y = fmaf(hhi(v.z), a1.y, b1.y);
    o1.z = fmaf(hlo(v.w), a1.z, b1.z);
    o1.w = fmaf(hhi(v.w), a1.w, b1.w);
    *(float4*)(out + off) = o0;
    *(float4*)(out + off + 4) = o1;
}

extern "C" void kernel_launch(void* const* d_in, const int* in_sizes, int n_in, void* d_out,
                              int out_size, void* d_ws, size_t ws_size, hipStream_t stream) {
    const float* x = (const float*)d_in[0];
    const int* esrc = (const int*)d_in[1];
    const int* edst = (const int*)d_in[2];
    const float* W1 = (const float*)d_in[3];
    const float* b1 = (const float*)d_in[4];
    const float* W2 = (const float*)d_in[5];
    const float* b2 = (const float*)d_in[6];
    const float* gamma = (const float*)d_in[7];
    const float* beta = (const float*)d_in[8];

    const int N = in_sizes[0] / D;
    const int E = in_sizes[1];
    const int L = in_sizes[3] / (D * D);
    const size_t nd = (size_t)N * D;
    const int nd8 = (int)(nd / 8);
    const int nbkt = (N + BKT_N - 1) >> BKT_SH;
    const int CH = (E + ABLK - 1) / ABLK;
    const int ntiles = (N + 31) / 32;

    // workspace layout (16B-aligned blocks first)
    char* ws = (char*)d_ws;
    uint* xh = (uint*)ws;          ws += nd * 2;                  // fp16 input
    uint* act0 = (uint*)ws;        ws += nd * 2;                  // ping
    uint* act1 = (uint*)ws;        ws += nd * 2;                  // pong
    uint* ubuf = (uint*)ws;        ws += nd * 2;                  // pre-affined MLP input u
    ushort* Wt1 = (ushort*)ws;     ws += (size_t)L * D * D * 2;
    ushort* Wt2 = (ushort*)ws;     ws += (size_t)L * D * D * 2;
    uint* staged = (uint*)ws;      ws += (size_t)E * 4;
    int* col_idx = (int*)ws;       ws += (size_t)E * 4;
    int* bcnt = (int*)ws;          ws += 256 * ABLK * 4;
    int* boff = (int*)ws;          ws += 256 * ABLK * 4;
    float* stats_mid = (float*)ws; ws += (size_t)3 * 32 * 256 * 4;  // per-layer regions
    float* ssall = (float*)ws;     ws += (size_t)(L + 1) * 256 * 4;
    int* bbase = (int*)ws;         ws += (256 + 1) * 4;
    int* row_start = (int*)ws;     ws += (size_t)(N + 1) * 4;

    // ---- one-time prep ----
    k_convert<<<(nd8 + 255) / 256, 256, 0, stream>>>(x, xh, nd8);
    k_prep_w<<<L, 256, 0, stream>>>(W1, W2, Wt1, Wt2);
    k_init<<<(3 * 32 * 256 + 255) / 256, 256, 0, stream>>>(ssall, stats_mid, 3 * 32 * 256);

    // ---- bucketed CSR build ----
    k_bcount<<<ABLK, 256, 0, stream>>>(edst, E, CH, nbkt, bcnt);
    k_bscan<<<1, 256, 0, stream>>>(bcnt, nbkt, boff, bbase, row_start, N, E);
    k_bscatter<<<ABLK, 256, 0, stream>>>(esrc, edst, E, CH, nbkt, boff, bbase, staged);
    k_bfill<<<nbkt, 256, 0, stream>>>(staged, bbase, N, row_start, col_idx);

    uint* bufs[2] = {act0, act1};
    const uint* cur_in = xh;
    dim3 ggrid((N + 31) / 32, 2);
    for (int l = 0; l < L; ++l) {
        uint* cur_out = bufs[l & 1];
        k_gather<<<ggrid, 256, 0, stream>>>(cur_in, row_start, col_idx,
                                            ssall + (size_t)l * 256, N, ubuf);
        k_mlp<<<NBMLP, 128, 0, stream>>>((const ushort*)ubuf, Wt1 + (size_t)l * D * D,
                                         b1 + (size_t)l * D, Wt2 + (size_t)l * D * D,
                                         b2 + (size_t)l * D, (ushort*)cur_out,
                                         stats_mid + (size_t)l * 32 * 256, N, ntiles);
        k_bnfin<<<1, 128, 0, stream>>>(stats_mid + (size_t)l * 32 * 256, gamma + (size_t)l * D,
                                       beta + (size_t)l * D, 1.0f / (float)N,
                                       ssall + (size_t)(l + 1) * 256);
        cur_in = cur_out;
    }
    k_norm_final<<<(nd8 + 255) / 256, 256, 0, stream>>>((const uint*)cur_in,
                                                        ssall + (size_t)L * 256, nd8,
                                                        (float*)d_out);
}

// Round 14
// 382.393 us; speedup vs baseline: 1.3857x; 1.0188x over previous
//
#include <hip/hip_runtime.h>
#include <cstddef>
#include <cstdint>

#define D 128
#define BN_EPS 1e-5f
#define BKT_SH 9               // 512 nodes per bucket
#define BKT_N 512
#define ABLK 256               // blocks in bucket passes
#define NBMLP 1024             // fixed mlp grid (grid-stride over tiles)
#define NS 8                   // stats slices

typedef _Float16 f16x8 __attribute__((ext_vector_type(8)));
typedef float f32x4 __attribute__((ext_vector_type(4)));

__device__ __forceinline__ ushort f2h(float f) {
    _Float16 h = (_Float16)f;
    ushort s;
    __builtin_memcpy(&s, &h, 2);
    return s;
}
__device__ __forceinline__ float hlo(uint v) {
    ushort s = (ushort)(v & 0xffffu);
    _Float16 h;
    __builtin_memcpy(&h, &s, 2);
    return (float)h;
}
__device__ __forceinline__ float hhi(uint v) {
    ushort s = (ushort)(v >> 16);
    _Float16 h;
    __builtin_memcpy(&h, &s, 2);
    return (float)h;
}

// cooperative BN-affine prologue: stats (NS slices) + gamma/beta -> LDS ss[256]
// ALL 256 threads must reach the barrier (call before any early return).
__device__ __forceinline__ void bn_affine_prologue(const float* stats, const float* gamma,
                                                   const float* beta, float ninv, int tid,
                                                   float* ss) {
    if (stats != nullptr) {
        if (tid < 128) {
            float s = 0.f, q = 0.f;
#pragma unroll
            for (int r = 0; r < NS; ++r) {
                s += stats[r * 256 + tid];
                q += stats[r * 256 + 128 + tid];
            }
            float mean = s * ninv;
            float var = fmaxf(q * ninv - mean * mean, 0.f);
            float a = gamma[tid] * rsqrtf(var + BN_EPS);
            ss[tid] = a;
            ss[128 + tid] = beta[tid] - mean * a;
        }
    } else {
        if (tid < 128) {
            ss[tid] = 1.f;
            ss[128 + tid] = 0.f;
        }
    }
    __syncthreads();
}

__global__ void k_zero_f(float* p, int n) {
    int i = blockIdx.x * blockDim.x + threadIdx.x;
    if (i < n) p[i] = 0.f;
}

// ---------------- bucketed CSR build (no global atomics) ----------------
__global__ __launch_bounds__(256) void k_bcount(const int* __restrict__ dst, int E, int CH,
                                                int nbkt, int* __restrict__ bcnt) {
    __shared__ int h[256];
    int tid = threadIdx.x;
    h[tid] = 0;
    __syncthreads();
    int s = blockIdx.x * CH, e = s + CH;
    if (e > E) e = E;
    for (int i = s + tid; i < e; i += 256) atomicAdd(&h[dst[i] >> BKT_SH], 1);
    __syncthreads();
    if (tid < nbkt) bcnt[tid * ABLK + blockIdx.x] = h[tid];
}

__global__ __launch_bounds__(256) void k_bscan(const int* __restrict__ bcnt, int nbkt,
                                               int* __restrict__ boff, int* __restrict__ bbase,
                                               int* __restrict__ row_start, int N, int E) {
    __shared__ int tot[256];
    int b = threadIdx.x;
    int t = 0;
    if (b < nbkt) {
        for (int i = 0; i < ABLK; ++i) {
            boff[b * ABLK + i] = t;
            t += bcnt[b * ABLK + i];
        }
    }
    tot[b] = t;
    __syncthreads();
    int v = t;
    for (int off = 1; off < 256; off <<= 1) {
        int u = (b >= off) ? tot[b - off] : 0;
        __syncthreads();
        tot[b] += u;
        __syncthreads();
    }
    if (b < nbkt) bbase[b] = tot[b] - v;
    if (b == 0) {
        bbase[nbkt] = E;
        row_start[N] = E;
    }
}

__global__ __launch_bounds__(256) void k_bscatter(const int* __restrict__ src,
                                                  const int* __restrict__ dst, int E, int CH,
                                                  int nbkt, const int* __restrict__ boff,
                                                  const int* __restrict__ bbase,
                                                  uint* __restrict__ staged) {
    __shared__ int cur[256];
    int tid = threadIdx.x;
    if (tid < nbkt) cur[tid] = bbase[tid] + boff[tid * ABLK + blockIdx.x];
    __syncthreads();
    int s = blockIdx.x * CH, e = s + CH;
    if (e > E) e = E;
    for (int i = s + tid; i < e; i += 256) {
        int d = dst[i];
        int b = d >> BKT_SH;
        int pos = atomicAdd(&cur[b], 1);
        staged[pos] = ((uint)(d & (BKT_N - 1)) << 23) | (uint)src[i];
    }
}

__global__ __launch_bounds__(256) void k_bfill(const uint* __restrict__ staged,
                                               const int* __restrict__ bbase, int N,
                                               int* __restrict__ row_start,
                                               int* __restrict__ col_idx) {
    __shared__ int cnt[BKT_N];
    __shared__ int sc[256];
    __shared__ int cur[BKT_N];
    int b = blockIdx.x, tid = threadIdx.x;
    cnt[tid] = 0;
    cnt[tid + 256] = 0;
    __syncthreads();
    int ebase = bbase[b], eend = bbase[b + 1];
    for (int i = ebase + tid; i < eend; i += 256) atomicAdd(&cnt[staged[i] >> 23], 1);
    __syncthreads();
    int c0 = cnt[2 * tid], c1 = cnt[2 * tid + 1], s = c0 + c1;
    sc[tid] = s;
    __syncthreads();
    for (int off = 1; off < 256; off <<= 1) {
        int u = (tid >= off) ? sc[tid - off] : 0;
        __syncthreads();
        sc[tid] += u;
        __syncthreads();
    }
    int ex = sc[tid] - s;
    int g0 = (b << BKT_SH) + 2 * tid;
    int p0 = ebase + ex, p1 = ebase + ex + c0;
    cur[2 * tid] = p0;
    cur[2 * tid + 1] = p1;
    if (g0 < N) row_start[g0] = p0;
    if (g0 + 1 < N) row_start[g0 + 1] = p1;
    __syncthreads();
    for (int i = ebase + tid; i < eend; i += 256) {
        uint w = staged[i];
        int pos = atomicAdd(&cur[w >> 23], 1);
        col_idx[pos] = (int)(w & 0x7FFFFFu);
    }
}

// ---------------- fp32 -> fp16 convert ----------------
__global__ void k_convert(const float* __restrict__ x, uint* __restrict__ xh, int nd8) {
    int i = blockIdx.x * blockDim.x + threadIdx.x;
    if (i >= nd8) return;
    size_t off = (size_t)i * 8;
    const float4* p = (const float4*)(x + off);
    float4 v0 = p[0], v1 = p[1];
    uint4 o;
    o.x = (uint)f2h(v0.x) | ((uint)f2h(v0.y) << 16);
    o.y = (uint)f2h(v0.z) | ((uint)f2h(v0.w) << 16);
    o.z = (uint)f2h(v1.x) | ((uint)f2h(v1.y) << 16);
    o.w = (uint)f2h(v1.z) | ((uint)f2h(v1.w) << 16);
    *(uint4*)(xh + off / 2) = o;
}

// ---------------- weight prep: both W1,W2 fp32 [k][c] -> fp16 [c][k], one launch ----
__global__ __launch_bounds__(256) void k_prep_w(const float* __restrict__ W1,
                                                const float* __restrict__ W2,
                                                ushort* __restrict__ Wt1,
                                                ushort* __restrict__ Wt2) {
    const float* src1 = W1 + (size_t)blockIdx.x * D * D;
    const float* src2 = W2 + (size_t)blockIdx.x * D * D;
    ushort* dst1 = Wt1 + (size_t)blockIdx.x * D * D;
    ushort* dst2 = Wt2 + (size_t)blockIdx.x * D * D;
#pragma unroll
    for (int i = 0; i < 64; ++i) {
        int idx = i * 256 + threadIdx.x;
        int k = idx >> 7, c = idx & 127;
        dst1[c * D + k] = f2h(src1[idx]);
        dst2[c * D + k] = f2h(src2[idx]);
    }
}

// ---------------- gather + inline BN-affine, HALF-ROW passes, unroll 4 ----------------
// gridDim.y = 2: pass y covers cols [y*64, y*64+64) = one 128B line per node.
// BN affine (a,b) recomputed per block from raw stats (cheap, L2-hot).
__global__ __launch_bounds__(256) void k_gather(const uint* __restrict__ xh,
                                                const int* __restrict__ rs,
                                                const int* __restrict__ col,
                                                const float* __restrict__ stats,
                                                const float* __restrict__ gamma,
                                                const float* __restrict__ beta, float ninv,
                                                int n, uint* __restrict__ U) {
    __shared__ float ss[256];
    int tid = threadIdx.x;
    bn_affine_prologue(stats, gamma, beta, ninv, tid, ss);

    int l8 = tid & 7;
    int half = blockIdx.y;
    int node = blockIdx.x * 32 + (tid >> 3);
    if (node >= n) return;
    const int cb = half * 64 + l8 * 8;
    const float4 A0 = *(const float4*)(ss + cb);
    const float4 A1 = *(const float4*)(ss + cb + 4);
    const float4 B0 = *(const float4*)(ss + 128 + cb);
    const float4 B1 = *(const float4*)(ss + 128 + cb + 4);
    const uint4* xr = (const uint4*)xh + half * 8 + l8;  // row r at xr[r*16]
    uint4 v = xr[(size_t)node * 16];
    float a0 = hlo(v.x), a1 = hhi(v.x), a2 = hlo(v.y), a3 = hhi(v.y);
    float a4 = hlo(v.z), a5 = hhi(v.z), a6 = hlo(v.w), a7 = hhi(v.w);
    int j0 = rs[node], e = rs[node + 1];
    int j = j0;
    for (; j + 4 <= e; j += 4) {
        int c0 = col[j], c1 = col[j + 1], c2 = col[j + 2], c3 = col[j + 3];
        uint4 u0 = xr[(size_t)c0 * 16];
        uint4 u1 = xr[(size_t)c1 * 16];
        uint4 u2 = xr[(size_t)c2 * 16];
        uint4 u3 = xr[(size_t)c3 * 16];
        a0 += (hlo(u0.x) + hlo(u1.x)) + (hlo(u2.x) + hlo(u3.x));
        a1 += (hhi(u0.x) + hhi(u1.x)) + (hhi(u2.x) + hhi(u3.x));
        a2 += (hlo(u0.y) + hlo(u1.y)) + (hlo(u2.y) + hlo(u3.y));
        a3 += (hhi(u0.y) + hhi(u1.y)) + (hhi(u2.y) + hhi(u3.y));
        a4 += (hlo(u0.z) + hlo(u1.z)) + (hlo(u2.z) + hlo(u3.z));
        a5 += (hhi(u0.z) + hhi(u1.z)) + (hhi(u2.z) + hhi(u3.z));
        a6 += (hlo(u0.w) + hlo(u1.w)) + (hlo(u2.w) + hlo(u3.w));
        a7 += (hhi(u0.w) + hhi(u1.w)) + (hhi(u2.w) + hhi(u3.w));
    }
    for (; j < e; ++j) {
        uint4 u = xr[(size_t)col[j] * 16];
        a0 += hlo(u.x);
        a1 += hhi(u.x);
        a2 += hlo(u.y);
        a3 += hhi(u.y);
        a4 += hlo(u.z);
        a5 += hhi(u.z);
        a6 += hlo(u.w);
        a7 += hhi(u.w);
    }
    float cnt = (float)(e - j0 + 1);
    float r0 = fmaf(A0.x, a0, cnt * B0.x);
    float r1 = fmaf(A0.y, a1, cnt * B0.y);
    float r2 = fmaf(A0.z, a2, cnt * B0.z);
    float r3 = fmaf(A0.w, a3, cnt * B0.w);
    float r4 = fmaf(A1.x, a4, cnt * B1.x);
    float r5 = fmaf(A1.y, a5, cnt * B1.y);
    float r6 = fmaf(A1.z, a6, cnt * B1.z);
    float r7 = fmaf(A1.w, a7, cnt * B1.w);
    uint4 o;
    o.x = (uint)f2h(r0) | ((uint)f2h(r1) << 16);
    o.y = (uint)f2h(r2) | ((uint)f2h(r3) << 16);
    o.z = (uint)f2h(r4) | ((uint)f2h(r5) << 16);
    o.w = (uint)f2h(r6) | ((uint)f2h(r7) << 16);
    ((uint4*)U)[(size_t)node * 16 + half * 8 + l8] = o;
}

// ---------------- MLP: weights register-resident, grid-stride over 32-row tiles --------
__global__ __launch_bounds__(128) void k_mlp(const ushort* __restrict__ U,
                                             const ushort* __restrict__ Wt1,
                                             const float* __restrict__ b1,
                                             const ushort* __restrict__ Wt2,
                                             const float* __restrict__ b2,
                                             ushort* __restrict__ hout,
                                             float* __restrict__ stats_mid, int n,
                                             int ntiles) {
    __shared__ ushort Hs[32 * D];  // 8 KB h1 tile, XOR-swizzled by 16B chunk
    __shared__ float sred[256];
    const int tid = threadIdx.x;
    sred[tid] = 0.f;
    sred[128 + tid] = 0.f;

    const int lane = tid & 63;
    const int wn = tid >> 6;  // column half
    const int l15 = lane & 15, lk = lane >> 4;

    // ---- hoist weight fragments into registers (once per block) ----
    f16x8 w1[4][4], w2[4][4];  // [ks][nn]
#pragma unroll
    for (int ks = 0; ks < 4; ++ks) {
        int k0 = ks * 32 + lk * 8;
#pragma unroll
        for (int nn = 0; nn < 4; ++nn) {
            int c = wn * 64 + nn * 16 + l15;
            w1[ks][nn] = *(const f16x8*)(Wt1 + (size_t)c * D + k0);
            w2[ks][nn] = *(const f16x8*)(Wt2 + (size_t)c * D + k0);
        }
    }
    float bc1[4], bc2[4];
#pragma unroll
    for (int nn = 0; nn < 4; ++nn) {
        bc1[nn] = b1[wn * 64 + nn * 16 + l15];
        bc2[nn] = b2[wn * 64 + nn * 16 + l15];
    }
    float cs[4] = {0.f, 0.f, 0.f, 0.f}, cq[4] = {0.f, 0.f, 0.f, 0.f};

    for (int t = blockIdx.x; t < ntiles; t += NBMLP) {
        const int rb = t * 32;
        f16x8 a[2][4];  // [m][ks]
#pragma unroll
        for (int ks = 0; ks < 4; ++ks) {
            int k0 = ks * 32 + lk * 8;
#pragma unroll
            for (int m = 0; m < 2; ++m) {
                int row = rb + m * 16 + l15;
                if (row > n - 1) row = n - 1;  // clamp; garbage rows never stored
                a[m][ks] = *(const f16x8*)(U + (size_t)row * D + k0);
            }
        }

        f32x4 acc[2][4];
#pragma unroll
        for (int m = 0; m < 2; ++m)
#pragma unroll
            for (int nn = 0; nn < 4; ++nn) acc[m][nn] = (f32x4){0.f, 0.f, 0.f, 0.f};

        // GEMM1 (all operands in registers)
#pragma unroll
        for (int ks = 0; ks < 4; ++ks)
#pragma unroll
            for (int m = 0; m < 2; ++m)
#pragma unroll
                for (int nn = 0; nn < 4; ++nn)
                    acc[m][nn] = __builtin_amdgcn_mfma_f32_16x16x32_f16(a[m][ks], w1[ks][nn],
                                                                        acc[m][nn], 0, 0, 0);

        __syncthreads();  // prev tile's GEMM2 reads of Hs complete before overwrite
        // epilogue1: h1 = relu(acc + b1) -> Hs (fp16, swizzled)
#pragma unroll
        for (int nn = 0; nn < 4; ++nn) {
            int cout = wn * 64 + nn * 16 + l15;
            int chv = cout >> 3, cw = cout & 7;
#pragma unroll
            for (int m = 0; m < 2; ++m)
#pragma unroll
                for (int r = 0; r < 4; ++r) {
                    int row = m * 16 + lk * 4 + r;
                    float v = fmaxf(acc[m][nn][r] + bc1[nn], 0.f);
                    Hs[row * D + ((chv ^ (row & 15)) << 3) + cw] = f2h(v);
                }
        }
        __syncthreads();

        // GEMM2: A = h1 from LDS, B = w2 registers
#pragma unroll
        for (int m = 0; m < 2; ++m)
#pragma unroll
            for (int nn = 0; nn < 4; ++nn) acc[m][nn] = (f32x4){0.f, 0.f, 0.f, 0.f};
#pragma unroll
        for (int ks = 0; ks < 4; ++ks) {
            f16x8 ah[2];
#pragma unroll
            for (int m = 0; m < 2; ++m) {
                int row = m * 16 + l15;
                ah[m] = *(const f16x8*)(Hs + row * D + (((ks * 4 + lk) ^ l15) << 3));
            }
#pragma unroll
            for (int m = 0; m < 2; ++m)
#pragma unroll
                for (int nn = 0; nn < 4; ++nn)
                    acc[m][nn] = __builtin_amdgcn_mfma_f32_16x16x32_f16(ah[m], w2[ks][nn],
                                                                        acc[m][nn], 0, 0, 0);
        }

        // epilogue2: h2 = relu(acc + b2) -> global fp16 + register stats
#pragma unroll
        for (int nn = 0; nn < 4; ++nn) {
            int c = wn * 64 + nn * 16 + l15;
#pragma unroll
            for (int m = 0; m < 2; ++m) {
                int rbase = rb + m * 16 + lk * 4;
#pragma unroll
                for (int r = 0; r < 4; ++r) {
                    if (rbase + r < n) {
                        float v = fmaxf(acc[m][nn][r] + bc2[nn], 0.f);
                        hout[(size_t)(rbase + r) * D + c] = f2h(v);
                        cs[nn] += v;
                        cq[nn] = fmaf(v, v, cq[nn]);
                    }
                }
            }
        }
    }

    // fold per-thread stats -> LDS -> NS-sliced global atomics
#pragma unroll
    for (int nn = 0; nn < 4; ++nn) {
        int c = wn * 64 + nn * 16 + l15;
        atomicAdd(&sred[c], cs[nn]);
        atomicAdd(&sred[128 + c], cq[nn]);
    }
    __syncthreads();
    float* sm = stats_mid + (size_t)(blockIdx.x & (NS - 1)) * 256;
    atomicAdd(&sm[tid], sred[tid]);
    atomicAdd(&sm[128 + tid], sred[128 + tid]);
}

// ---------------- final normalize (inline BN affine): out = a*h + b (fp32) --------
__global__ __launch_bounds__(256) void k_norm_final(const uint* __restrict__ h,
                                                    const float* __restrict__ stats,
                                                    const float* __restrict__ gamma,
                                                    const float* __restrict__ beta, float ninv,
                                                    int nd8, float* __restrict__ out) {
    __shared__ float ss[256];
    int tid = threadIdx.x;
    bn_affine_prologue(stats, gamma, beta, ninv, tid, ss);

    int i = blockIdx.x * blockDim.x + tid;
    if (i >= nd8) return;
    size_t off = (size_t)i * 8;
    int c = (int)(off & (D - 1));
    uint4 v = *(const uint4*)(h + off / 2);
    float4 a0 = *(const float4*)(ss + c), a1 = *(const float4*)(ss + c + 4);
    float4 b0 = *(const float4*)(ss + 128 + c), b1 = *(const float4*)(ss + 132 + c);
    float4 o0, o1;
    o0.x = fmaf(hlo(v.x), a0.x, b0.x);
    o0.y = fmaf(hhi(v.x), a0.y, b0.y);
    o0.z = fmaf(hlo(v.y), a0.z, b0.z);
    o0.w = fmaf(hhi(v.y), a0.w, b0.w);
    o1.x = fmaf(hlo(v.z), a1.x, b1.x);
    o1.y = fmaf(hhi(v.z), a1.y, b1.y);
    o1.z = fmaf(hlo(v.w), a1.z, b1.z);
    o1.w = fmaf(hhi(v.w), a1.w, b1.w);
    *(float4*)(out + off) = o0;
    *(float4*)(out + off + 4) = o1;
}

extern "C" void kernel_launch(void* const* d_in, const int* in_sizes, int n_in, void* d_out,
                              int out_size, void* d_ws, size_t ws_size, hipStream_t stream) {
    const float* x = (const float*)d_in[0];
    const int* esrc = (const int*)d_in[1];
    const int* edst = (const int*)d_in[2];
    const float* W1 = (const float*)d_in[3];
    const float* b1 = (const float*)d_in[4];
    const float* W2 = (const float*)d_in[5];
    const float* b2 = (const float*)d_in[6];
    const float* gamma = (const float*)d_in[7];
    const float* beta = (const float*)d_in[8];

    const int N = in_sizes[0] / D;
    const int E = in_sizes[1];
    const int L = in_sizes[3] / (D * D);
    const size_t nd = (size_t)N * D;
    const int nd8 = (int)(nd / 8);
    const int nbkt = (N + BKT_N - 1) >> BKT_SH;
    const int CH = (E + ABLK - 1) / ABLK;
    const int ntiles = (N + 31) / 32;
    const float ninv = 1.0f / (float)N;

    // workspace layout (16B-aligned blocks first)
    char* ws = (char*)d_ws;
    uint* xh = (uint*)ws;          ws += nd * 2;                  // fp16 input
    uint* act0 = (uint*)ws;        ws += nd * 2;                  // ping
    uint* act1 = (uint*)ws;        ws += nd * 2;                  // pong
    uint* ubuf = (uint*)ws;        ws += nd * 2;                  // pre-affined MLP input u
    ushort* Wt1 = (ushort*)ws;     ws += (size_t)L * D * D * 2;
    ushort* Wt2 = (ushort*)ws;     ws += (size_t)L * D * D * 2;
    uint* staged = (uint*)ws;      ws += (size_t)E * 4;
    int* col_idx = (int*)ws;       ws += (size_t)E * 4;
    int* bcnt = (int*)ws;          ws += 256 * ABLK * 4;
    int* boff = (int*)ws;          ws += 256 * ABLK * 4;
    float* stats_mid = (float*)ws; ws += (size_t)3 * NS * 256 * 4;  // per-layer regions
    int* bbase = (int*)ws;         ws += (256 + 1) * 4;
    int* row_start = (int*)ws;     ws += (size_t)(N + 1) * 4;

    // ---- one-time prep ----
    k_convert<<<(nd8 + 255) / 256, 256, 0, stream>>>(x, xh, nd8);
    k_prep_w<<<L, 256, 0, stream>>>(W1, W2, Wt1, Wt2);
    k_zero_f<<<(3 * NS * 256 + 255) / 256, 256, 0, stream>>>(stats_mid, 3 * NS * 256);

    // ---- bucketed CSR build ----
    k_bcount<<<ABLK, 256, 0, stream>>>(edst, E, CH, nbkt, bcnt);
    k_bscan<<<1, 256, 0, stream>>>(bcnt, nbkt, boff, bbase, row_start, N, E);
    k_bscatter<<<ABLK, 256, 0, stream>>>(esrc, edst, E, CH, nbkt, boff, bbase, staged);
    k_bfill<<<nbkt, 256, 0, stream>>>(staged, bbase, N, row_start, col_idx);

    uint* bufs[2] = {act0, act1};
    const uint* cur_in = xh;
    dim3 ggrid((N + 31) / 32, 2);
    for (int l = 0; l < L; ++l) {
        uint* cur_out = bufs[l & 1];
        const float* st = (l == 0) ? nullptr : stats_mid + (size_t)(l - 1) * NS * 256;
        const float* gm = (l == 0) ? nullptr : gamma + (size_t)(l - 1) * D;
        const float* bt = (l == 0) ? nullptr : beta + (size_t)(l - 1) * D;
        k_gather<<<ggrid, 256, 0, stream>>>(cur_in, row_start, col_idx, st, gm, bt, ninv, N,
                                            ubuf);
        k_mlp<<<NBMLP, 128, 0, stream>>>((const ushort*)ubuf, Wt1 + (size_t)l * D * D,
                                         b1 + (size_t)l * D, Wt2 + (size_t)l * D * D,
                                         b2 + (size_t)l * D, (ushort*)cur_out,
                                         stats_mid + (size_t)l * NS * 256, N, ntiles);
        cur_in = cur_out;
    }
    k_norm_final<<<(nd8 + 255) / 256, 256, 0, stream>>>(
        (const uint*)cur_in, stats_mid + (size_t)(L - 1) * NS * 256,
        gamma + (size_t)(L - 1) * D, beta + (size_t)(L - 1) * D, ninv, nd8, (float*)d_out);
}

// Round 15
// 379.038 us; speedup vs baseline: 1.3980x; 1.0089x over previous
//
#include <hip/hip_runtime.h>
#include <cstddef>
#include <cstdint>

#define D 128
#define BN_EPS 1e-5f
#define BKT_SH 9               // 512 nodes per bucket
#define BKT_N 512
#define ABLK 256               // blocks in bucket passes
#define NBMLP 1024             // fixed mlp grid (grid-stride over tiles)
#define NS 8                   // stats slices

typedef _Float16 f16x8 __attribute__((ext_vector_type(8)));
typedef float f32x4 __attribute__((ext_vector_type(4)));

__device__ __forceinline__ ushort f2h(float f) {
    _Float16 h = (_Float16)f;
    ushort s;
    __builtin_memcpy(&s, &h, 2);
    return s;
}
__device__ __forceinline__ float hlo(uint v) {
    ushort s = (ushort)(v & 0xffffu);
    _Float16 h;
    __builtin_memcpy(&h, &s, 2);
    return (float)h;
}
__device__ __forceinline__ float hhi(uint v) {
    ushort s = (ushort)(v >> 16);
    _Float16 h;
    __builtin_memcpy(&h, &s, 2);
    return (float)h;
}

// cooperative BN-affine prologue: stats (NS slices) + gamma/beta -> LDS ss[256]
__device__ __forceinline__ void bn_affine_prologue(const float* stats, const float* gamma,
                                                   const float* beta, float ninv, int tid,
                                                   float* ss) {
    if (stats != nullptr) {
        if (tid < 128) {
            float s = 0.f, q = 0.f;
#pragma unroll
            for (int r = 0; r < NS; ++r) {
                s += stats[r * 256 + tid];
                q += stats[r * 256 + 128 + tid];
            }
            float mean = s * ninv;
            float var = fmaxf(q * ninv - mean * mean, 0.f);
            float a = gamma[tid] * rsqrtf(var + BN_EPS);
            ss[tid] = a;
            ss[128 + tid] = beta[tid] - mean * a;
        }
    } else {
        if (tid < 128) {
            ss[tid] = 1.f;
            ss[128 + tid] = 0.f;
        }
    }
    __syncthreads();
}

// ---------------- bucketed CSR build (no global atomics) ----------------
// bcnt/boff layout: [block][bucket] (coalesced everywhere). Blocks 0..23 also
// zero the 3*NS*256 stats floats (independent memory, no sync needed).
__global__ __launch_bounds__(256) void k_bcount(const int* __restrict__ dst, int E, int CH,
                                                int nbkt, int* __restrict__ bcnt,
                                                float* __restrict__ stats, int nstats) {
    __shared__ int h[256];
    int tid = threadIdx.x;
    int zi = blockIdx.x * 256 + tid;
    if (zi < nstats) stats[zi] = 0.f;
    h[tid] = 0;
    __syncthreads();
    int s = blockIdx.x * CH, e = s + CH;
    if (e > E) e = E;
    for (int i = s + tid; i < e; i += 256) atomicAdd(&h[dst[i] >> BKT_SH], 1);
    __syncthreads();
    bcnt[blockIdx.x * 256 + tid] = h[tid];
}

// single block; per-iteration accesses coalesced across buckets (lanes = buckets)
__global__ __launch_bounds__(256) void k_bscan(const int* __restrict__ bcnt, int nbkt,
                                               int* __restrict__ boff, int* __restrict__ bbase,
                                               int* __restrict__ row_start, int N, int E) {
    __shared__ int tot[256];
    int b = threadIdx.x;
    int t = 0;
#pragma unroll 4
    for (int i = 0; i < ABLK; ++i) {
        int c = bcnt[i * 256 + b];
        boff[i * 256 + b] = t;
        t += c;
    }
    tot[b] = t;
    __syncthreads();
    int v = t;
    for (int off = 1; off < 256; off <<= 1) {
        int u = (b >= off) ? tot[b - off] : 0;
        __syncthreads();
        tot[b] += u;
        __syncthreads();
    }
    if (b < nbkt) bbase[b] = tot[b] - v;
    if (b == 0) {
        bbase[nbkt] = E;
        row_start[N] = E;
    }
}

__global__ __launch_bounds__(256) void k_bscatter(const int* __restrict__ src,
                                                  const int* __restrict__ dst, int E, int CH,
                                                  int nbkt, const int* __restrict__ boff,
                                                  const int* __restrict__ bbase,
                                                  uint* __restrict__ staged) {
    __shared__ int cur[256];
    int tid = threadIdx.x;
    if (tid < nbkt) cur[tid] = bbase[tid] + boff[blockIdx.x * 256 + tid];
    __syncthreads();
    int s = blockIdx.x * CH, e = s + CH;
    if (e > E) e = E;
    for (int i = s + tid; i < e; i += 256) {
        int d = dst[i];
        int b = d >> BKT_SH;
        int pos = atomicAdd(&cur[b], 1);
        staged[pos] = ((uint)(d & (BKT_N - 1)) << 23) | (uint)src[i];
    }
}

__global__ __launch_bounds__(256) void k_bfill(const uint* __restrict__ staged,
                                               const int* __restrict__ bbase, int N,
                                               int* __restrict__ row_start,
                                               int* __restrict__ col_idx) {
    __shared__ int cnt[BKT_N];
    __shared__ int sc[256];
    __shared__ int cur[BKT_N];
    int b = blockIdx.x, tid = threadIdx.x;
    cnt[tid] = 0;
    cnt[tid + 256] = 0;
    __syncthreads();
    int ebase = bbase[b], eend = bbase[b + 1];
    for (int i = ebase + tid; i < eend; i += 256) atomicAdd(&cnt[staged[i] >> 23], 1);
    __syncthreads();
    int c0 = cnt[2 * tid], c1 = cnt[2 * tid + 1], s = c0 + c1;
    sc[tid] = s;
    __syncthreads();
    for (int off = 1; off < 256; off <<= 1) {
        int u = (tid >= off) ? sc[tid - off] : 0;
        __syncthreads();
        sc[tid] += u;
        __syncthreads();
    }
    int ex = sc[tid] - s;
    int g0 = (b << BKT_SH) + 2 * tid;
    int p0 = ebase + ex, p1 = ebase + ex + c0;
    cur[2 * tid] = p0;
    cur[2 * tid + 1] = p1;
    if (g0 < N) row_start[g0] = p0;
    if (g0 + 1 < N) row_start[g0 + 1] = p1;
    __syncthreads();
    for (int i = ebase + tid; i < eend; i += 256) {
        uint w = staged[i];
        int pos = atomicAdd(&cur[w >> 23], 1);
        col_idx[pos] = (int)(w & 0x7FFFFFu);
    }
}

// ---------------- fp32 -> fp16 convert + weight prep (fused launch) ----------------
// blocks [0, nb_conv): convert x; blocks [nb_conv, nb_conv+L): transpose W1/W2 layer.
__global__ __launch_bounds__(256) void k_convert(const float* __restrict__ x,
                                                 uint* __restrict__ xh, int nd8, int nb_conv,
                                                 const float* __restrict__ W1,
                                                 const float* __restrict__ W2,
                                                 ushort* __restrict__ Wt1,
                                                 ushort* __restrict__ Wt2) {
    if ((int)blockIdx.x >= nb_conv) {
        int l = blockIdx.x - nb_conv;
        const float* src1 = W1 + (size_t)l * D * D;
        const float* src2 = W2 + (size_t)l * D * D;
        ushort* dst1 = Wt1 + (size_t)l * D * D;
        ushort* dst2 = Wt2 + (size_t)l * D * D;
#pragma unroll
        for (int i = 0; i < 64; ++i) {
            int idx = i * 256 + threadIdx.x;
            int k = idx >> 7, c = idx & 127;
            dst1[c * D + k] = f2h(src1[idx]);
            dst2[c * D + k] = f2h(src2[idx]);
        }
        return;
    }
    int i = blockIdx.x * blockDim.x + threadIdx.x;
    if (i >= nd8) return;
    size_t off = (size_t)i * 8;
    const float4* p = (const float4*)(x + off);
    float4 v0 = p[0], v1 = p[1];
    uint4 o;
    o.x = (uint)f2h(v0.x) | ((uint)f2h(v0.y) << 16);
    o.y = (uint)f2h(v0.z) | ((uint)f2h(v0.w) << 16);
    o.z = (uint)f2h(v1.x) | ((uint)f2h(v1.y) << 16);
    o.w = (uint)f2h(v1.z) | ((uint)f2h(v1.w) << 16);
    *(uint4*)(xh + off / 2) = o;
}

// ---------------- gather + inline BN-affine, HALF-ROW passes, unroll 4 ----------------
__global__ __launch_bounds__(256) void k_gather(const uint* __restrict__ xh,
                                                const int* __restrict__ rs,
                                                const int* __restrict__ col,
                                                const float* __restrict__ stats,
                                                const float* __restrict__ gamma,
                                                const float* __restrict__ beta, float ninv,
                                                int n, uint* __restrict__ U) {
    __shared__ float ss[256];
    int tid = threadIdx.x;
    bn_affine_prologue(stats, gamma, beta, ninv, tid, ss);

    int l8 = tid & 7;
    int half = blockIdx.y;
    int node = blockIdx.x * 32 + (tid >> 3);
    if (node >= n) return;
    const int cb = half * 64 + l8 * 8;
    const float4 A0 = *(const float4*)(ss + cb);
    const float4 A1 = *(const float4*)(ss + cb + 4);
    const float4 B0 = *(const float4*)(ss + 128 + cb);
    const float4 B1 = *(const float4*)(ss + 128 + cb + 4);
    const uint4* xr = (const uint4*)xh + half * 8 + l8;  // row r at xr[r*16]
    uint4 v = xr[(size_t)node * 16];
    float a0 = hlo(v.x), a1 = hhi(v.x), a2 = hlo(v.y), a3 = hhi(v.y);
    float a4 = hlo(v.z), a5 = hhi(v.z), a6 = hlo(v.w), a7 = hhi(v.w);
    int j0 = rs[node], e = rs[node + 1];
    int j = j0;
    for (; j + 4 <= e; j += 4) {
        int c0 = col[j], c1 = col[j + 1], c2 = col[j + 2], c3 = col[j + 3];
        uint4 u0 = xr[(size_t)c0 * 16];
        uint4 u1 = xr[(size_t)c1 * 16];
        uint4 u2 = xr[(size_t)c2 * 16];
        uint4 u3 = xr[(size_t)c3 * 16];
        a0 += (hlo(u0.x) + hlo(u1.x)) + (hlo(u2.x) + hlo(u3.x));
        a1 += (hhi(u0.x) + hhi(u1.x)) + (hhi(u2.x) + hhi(u3.x));
        a2 += (hlo(u0.y) + hlo(u1.y)) + (hlo(u2.y) + hlo(u3.y));
        a3 += (hhi(u0.y) + hhi(u1.y)) + (hhi(u2.y) + hhi(u3.y));
        a4 += (hlo(u0.z) + hlo(u1.z)) + (hlo(u2.z) + hlo(u3.z));
        a5 += (hhi(u0.z) + hhi(u1.z)) + (hhi(u2.z) + hhi(u3.z));
        a6 += (hlo(u0.w) + hlo(u1.w)) + (hlo(u2.w) + hlo(u3.w));
        a7 += (hhi(u0.w) + hhi(u1.w)) + (hhi(u2.w) + hhi(u3.w));
    }
    for (; j < e; ++j) {
        uint4 u = xr[(size_t)col[j] * 16];
        a0 += hlo(u.x);
        a1 += hhi(u.x);
        a2 += hlo(u.y);
        a3 += hhi(u.y);
        a4 += hlo(u.z);
        a5 += hhi(u.z);
        a6 += hlo(u.w);
        a7 += hhi(u.w);
    }
    float cnt = (float)(e - j0 + 1);
    float r0 = fmaf(A0.x, a0, cnt * B0.x);
    float r1 = fmaf(A0.y, a1, cnt * B0.y);
    float r2 = fmaf(A0.z, a2, cnt * B0.z);
    float r3 = fmaf(A0.w, a3, cnt * B0.w);
    float r4 = fmaf(A1.x, a4, cnt * B1.x);
    float r5 = fmaf(A1.y, a5, cnt * B1.y);
    float r6 = fmaf(A1.z, a6, cnt * B1.z);
    float r7 = fmaf(A1.w, a7, cnt * B1.w);
    uint4 o;
    o.x = (uint)f2h(r0) | ((uint)f2h(r1) << 16);
    o.y = (uint)f2h(r2) | ((uint)f2h(r3) << 16);
    o.z = (uint)f2h(r4) | ((uint)f2h(r5) << 16);
    o.w = (uint)f2h(r6) | ((uint)f2h(r7) << 16);
    ((uint4*)U)[(size_t)node * 16 + half * 8 + l8] = o;
}

// ---------------- MLP: weights register-resident, grid-stride over 32-row tiles --------
__global__ __launch_bounds__(128) void k_mlp(const ushort* __restrict__ U,
                                             const ushort* __restrict__ Wt1,
                                             const float* __restrict__ b1,
                                             const ushort* __restrict__ Wt2,
                                             const float* __restrict__ b2,
                                             ushort* __restrict__ hout,
                                             float* __restrict__ stats_mid, int n,
                                             int ntiles) {
    __shared__ ushort Hs[32 * D];  // 8 KB h1 tile, XOR-swizzled by 16B chunk
    __shared__ float sred[256];
    const int tid = threadIdx.x;
    sred[tid] = 0.f;
    sred[128 + tid] = 0.f;

    const int lane = tid & 63;
    const int wn = tid >> 6;  // column half
    const int l15 = lane & 15, lk = lane >> 4;

    f16x8 w1[4][4], w2[4][4];  // [ks][nn]
#pragma unroll
    for (int ks = 0; ks < 4; ++ks) {
        int k0 = ks * 32 + lk * 8;
#pragma unroll
        for (int nn = 0; nn < 4; ++nn) {
            int c = wn * 64 + nn * 16 + l15;
            w1[ks][nn] = *(const f16x8*)(Wt1 + (size_t)c * D + k0);
            w2[ks][nn] = *(const f16x8*)(Wt2 + (size_t)c * D + k0);
        }
    }
    float bc1[4], bc2[4];
#pragma unroll
    for (int nn = 0; nn < 4; ++nn) {
        bc1[nn] = b1[wn * 64 + nn * 16 + l15];
        bc2[nn] = b2[wn * 64 + nn * 16 + l15];
    }
    float cs[4] = {0.f, 0.f, 0.f, 0.f}, cq[4] = {0.f, 0.f, 0.f, 0.f};

    for (int t = blockIdx.x; t < ntiles; t += NBMLP) {
        const int rb = t * 32;
        f16x8 a[2][4];  // [m][ks]
#pragma unroll
        for (int ks = 0; ks < 4; ++ks) {
            int k0 = ks * 32 + lk * 8;
#pragma unroll
            for (int m = 0; m < 2; ++m) {
                int row = rb + m * 16 + l15;
                if (row > n - 1) row = n - 1;  // clamp; garbage rows never stored
                a[m][ks] = *(const f16x8*)(U + (size_t)row * D + k0);
            }
        }

        f32x4 acc[2][4];
#pragma unroll
        for (int m = 0; m < 2; ++m)
#pragma unroll
            for (int nn = 0; nn < 4; ++nn) acc[m][nn] = (f32x4){0.f, 0.f, 0.f, 0.f};

#pragma unroll
        for (int ks = 0; ks < 4; ++ks)
#pragma unroll
            for (int m = 0; m < 2; ++m)
#pragma unroll
                for (int nn = 0; nn < 4; ++nn)
                    acc[m][nn] = __builtin_amdgcn_mfma_f32_16x16x32_f16(a[m][ks], w1[ks][nn],
                                                                        acc[m][nn], 0, 0, 0);

        __syncthreads();  // prev tile's GEMM2 reads of Hs complete before overwrite
#pragma unroll
        for (int nn = 0; nn < 4; ++nn) {
            int cout = wn * 64 + nn * 16 + l15;
            int chv = cout >> 3, cw = cout & 7;
#pragma unroll
            for (int m = 0; m < 2; ++m)
#pragma unroll
                for (int r = 0; r < 4; ++r) {
                    int row = m * 16 + lk * 4 + r;
                    float v = fmaxf(acc[m][nn][r] + bc1[nn], 0.f);
                    Hs[row * D + ((chv ^ (row & 15)) << 3) + cw] = f2h(v);
                }
        }
        __syncthreads();

#pragma unroll
        for (int m = 0; m < 2; ++m)
#pragma unroll
            for (int nn = 0; nn < 4; ++nn) acc[m][nn] = (f32x4){0.f, 0.f, 0.f, 0.f};
#pragma unroll
        for (int ks = 0; ks < 4; ++ks) {
            f16x8 ah[2];
#pragma unroll
            for (int m = 0; m < 2; ++m) {
                int row = m * 16 + l15;
                ah[m] = *(const f16x8*)(Hs + row * D + (((ks * 4 + lk) ^ l15) << 3));
            }
#pragma unroll
            for (int m = 0; m < 2; ++m)
#pragma unroll
                for (int nn = 0; nn < 4; ++nn)
                    acc[m][nn] = __builtin_amdgcn_mfma_f32_16x16x32_f16(ah[m], w2[ks][nn],
                                                                        acc[m][nn], 0, 0, 0);
        }

#pragma unroll
        for (int nn = 0; nn < 4; ++nn) {
            int c = wn * 64 + nn * 16 + l15;
#pragma unroll
            for (int m = 0; m < 2; ++m) {
                int rbase = rb + m * 16 + lk * 4;
#pragma unroll
                for (int r = 0; r < 4; ++r) {
                    if (rbase + r < n) {
                        float v = fmaxf(acc[m][nn][r] + bc2[nn], 0.f);
                        hout[(size_t)(rbase + r) * D + c] = f2h(v);
                        cs[nn] += v;
                        cq[nn] = fmaf(v, v, cq[nn]);
                    }
                }
            }
        }
    }

#pragma unroll
    for (int nn = 0; nn < 4; ++nn) {
        int c = wn * 64 + nn * 16 + l15;
        atomicAdd(&sred[c], cs[nn]);
        atomicAdd(&sred[128 + c], cq[nn]);
    }
    __syncthreads();
    float* sm = stats_mid + (size_t)(blockIdx.x & (NS - 1)) * 256;
    atomicAdd(&sm[tid], sred[tid]);
    atomicAdd(&sm[128 + tid], sred[128 + tid]);
}

// ---------------- final normalize (inline BN affine): out = a*h + b (fp32) --------
__global__ __launch_bounds__(256) void k_norm_final(const uint* __restrict__ h,
                                                    const float* __restrict__ stats,
                                                    const float* __restrict__ gamma,
                                                    const float* __restrict__ beta, float ninv,
                                                    int nd8, float* __restrict__ out) {
    __shared__ float ss[256];
    int tid = threadIdx.x;
    bn_affine_prologue(stats, gamma, beta, ninv, tid, ss);

    int i = blockIdx.x * blockDim.x + tid;
    if (i >= nd8) return;
    size_t off = (size_t)i * 8;
    int c = (int)(off & (D - 1));
    uint4 v = *(const uint4*)(h + off / 2);
    float4 a0 = *(const float4*)(ss + c), a1 = *(const float4*)(ss + c + 4);
    float4 b0 = *(const float4*)(ss + 128 + c), b1 = *(const float4*)(ss + 132 + c);
    float4 o0, o1;
    o0.x = fmaf(hlo(v.x), a0.x, b0.x);
    o0.y = fmaf(hhi(v.x), a0.y, b0.y);
    o0.z = fmaf(hlo(v.y), a0.z, b0.z);
    o0.w = fmaf(hhi(v.y), a0.w, b0.w);
    o1.x = fmaf(hlo(v.z), a1.x, b1.x);
    o1.y = fmaf(hhi(v.z), a1.y, b1.y);
    o1.z = fmaf(hlo(v.w), a1.z, b1.z);
    o1.w = fmaf(hhi(v.w), a1.w, b1.w);
    *(float4*)(out + off) = o0;
    *(float4*)(out + off + 4) = o1;
}

extern "C" void kernel_launch(void* const* d_in, const int* in_sizes, int n_in, void* d_out,
                              int out_size, void* d_ws, size_t ws_size, hipStream_t stream) {
    const float* x = (const float*)d_in[0];
    const int* esrc = (const int*)d_in[1];
    const int* edst = (const int*)d_in[2];
    const float* W1 = (const float*)d_in[3];
    const float* b1 = (const float*)d_in[4];
    const float* W2 = (const float*)d_in[5];
    const float* b2 = (const float*)d_in[6];
    const float* gamma = (const float*)d_in[7];
    const float* beta = (const float*)d_in[8];

    const int N = in_sizes[0] / D;
    const int E = in_sizes[1];
    const int L = in_sizes[3] / (D * D);
    const size_t nd = (size_t)N * D;
    const int nd8 = (int)(nd / 8);
    const int nbkt = (N + BKT_N - 1) >> BKT_SH;
    const int CH = (E + ABLK - 1) / ABLK;
    const int ntiles = (N + 31) / 32;
    const float ninv = 1.0f / (float)N;
    const int nb_conv = (nd8 + 255) / 256;

    // workspace layout (16B-aligned blocks first)
    char* ws = (char*)d_ws;
    uint* xh = (uint*)ws;          ws += nd * 2;                  // fp16 input
    uint* act0 = (uint*)ws;        ws += nd * 2;                  // ping
    uint* act1 = (uint*)ws;        ws += nd * 2;                  // pong
    uint* ubuf = (uint*)ws;        ws += nd * 2;                  // pre-affined MLP input u
    ushort* Wt1 = (ushort*)ws;     ws += (size_t)L * D * D * 2;
    ushort* Wt2 = (ushort*)ws;     ws += (size_t)L * D * D * 2;
    uint* staged = (uint*)ws;      ws += (size_t)E * 4;
    int* col_idx = (int*)ws;       ws += (size_t)E * 4;
    int* bcnt = (int*)ws;          ws += 256 * ABLK * 4;
    int* boff = (int*)ws;          ws += 256 * ABLK * 4;
    float* stats_mid = (float*)ws; ws += (size_t)3 * NS * 256 * 4;  // per-layer regions
    int* bbase = (int*)ws;         ws += (256 + 1) * 4;
    int* row_start = (int*)ws;     ws += (size_t)(N + 1) * 4;

    // ---- one-time prep (convert + weight transpose fused) ----
    k_convert<<<nb_conv + L, 256, 0, stream>>>(x, xh, nd8, nb_conv, W1, W2, Wt1, Wt2);

    // ---- bucketed CSR build (stats zero folded into bcount) ----
    k_bcount<<<ABLK, 256, 0, stream>>>(edst, E, CH, nbkt, bcnt, stats_mid, 3 * NS * 256);
    k_bscan<<<1, 256, 0, stream>>>(bcnt, nbkt, boff, bbase, row_start, N, E);
    k_bscatter<<<ABLK, 256, 0, stream>>>(esrc, edst, E, CH, nbkt, boff, bbase, staged);
    k_bfill<<<nbkt, 256, 0, stream>>>(staged, bbase, N, row_start, col_idx);

    uint* bufs[2] = {act0, act1};
    const uint* cur_in = xh;
    dim3 ggrid((N + 31) / 32, 2);
    for (int l = 0; l < L; ++l) {
        uint* cur_out = bufs[l & 1];
        const float* st = (l == 0) ? nullptr : stats_mid + (size_t)(l - 1) * NS * 256;
        const float* gm = (l == 0) ? nullptr : gamma + (size_t)(l - 1) * D;
        const float* bt = (l == 0) ? nullptr : beta + (size_t)(l - 1) * D;
        k_gather<<<ggrid, 256, 0, stream>>>(cur_in, row_start, col_idx, st, gm, bt, ninv, N,
                                            ubuf);
        k_mlp<<<NBMLP, 128, 0, stream>>>((const ushort*)ubuf, Wt1 + (size_t)l * D * D,
                                         b1 + (size_t)l * D, Wt2 + (size_t)l * D * D,
                                         b2 + (size_t)l * D, (ushort*)cur_out,
                                         stats_mid + (size_t)l * NS * 256, N, ntiles);
        cur_in = cur_out;
    }
    k_norm_final<<<(nd8 + 255) / 256, 256, 0, stream>>>(
        (const uint*)cur_in, stats_mid + (size_t)(L - 1) * NS * 256,
        gamma + (size_t)(L - 1) * D, beta + (size_t)(L - 1) * D, ninv, nd8, (float*)d_out);
}